// Round 6
// baseline (109.916 us; speedup 1.0000x reference)
//
#include <hip/hip_runtime.h>
#include <hip/hip_bf16.h>
#include <math.h>

#define DD 1024          // D (in == out features)
#define BT 8192          // B*N tokens
#define TWO_PI 6.28318530717958647692f

typedef float f32x4 __attribute__((ext_vector_type(4)));
typedef short bf16x8 __attribute__((ext_vector_type(8)));
typedef unsigned short u16x8 __attribute__((ext_vector_type(8)));
typedef unsigned short u16x4 __attribute__((ext_vector_type(4)));
typedef const __attribute__((address_space(1))) void g_void;
typedef __attribute__((address_space(3))) void l_void;

__device__ __forceinline__ unsigned short f2bf(float f) {
  unsigned int u = __float_as_uint(f);
  unsigned int r = (u + 0x7FFFu + ((u >> 16) & 1u)) >> 16;   // RNE
  return (unsigned short)r;
}

// ---------------------------------------------------------------------------
// Transpose W (Wr,Wi fp32 (k,o)) -> Wt float2 (o,k), coalesced both sides.
// ---------------------------------------------------------------------------
__global__ __launch_bounds__(256) void transpose_W_kernel(
    const float* __restrict__ Wr, const float* __restrict__ Wi,
    float2* __restrict__ Wt) {
  __shared__ float tr[64][65];
  __shared__ float ti[64][65];
  const int k0 = blockIdx.y * 64, o0 = blockIdx.x * 64;
  for (int q = threadIdx.x; q < 64 * 64; q += 256) {
    int r = q >> 6, c = q & 63;                 // r: k, c: o
    tr[r][c] = Wr[(size_t)(k0 + r) * DD + o0 + c];
    ti[r][c] = Wi[(size_t)(k0 + r) * DD + o0 + c];
  }
  __syncthreads();
  for (int q = threadIdx.x; q < 64 * 64; q += 256) {
    int r = q >> 6, c = q & 63;                 // r: o, c: k
    Wt[(size_t)(o0 + r) * DD + k0 + c] = make_float2(tr[c][r], ti[c][r]);
  }
}

// ---------------------------------------------------------------------------
// T[o][d] = sum_k W[k][o] e^{-2pi i k d/D}. One block per o; compact nonzeros
// of row Wt[o][:] (coalesced) into LDS (parallel prefix), then twiddle table.
// ---------------------------------------------------------------------------
__global__ __launch_bounds__(256) void build_T_kernel(
    const float2* __restrict__ Wt, float2* __restrict__ T) {
  __shared__ float2 tw[DD];
  __shared__ int    kidx[64];
  __shared__ float2 wval[64];
  __shared__ int    sc[256];
  const int o = blockIdx.x, tid = threadIdx.x;

  for (int j = tid; j < DD; j += 256) {
    float s, c;
    sincosf((TWO_PI / DD) * (float)j, &s, &c);
    tw[j] = make_float2(c, s);
  }
  int cnt = 0;
  float2 wl[4];
  int    kl[4];
#pragma unroll
  for (int q = 0; q < 4; q++) {
    int k = tid + q * 256;
    float2 w = Wt[(size_t)o * DD + k];
    if (w.x != 0.f || w.y != 0.f) { wl[cnt] = w; kl[cnt] = k; cnt++; }
  }
  sc[tid] = cnt;
  __syncthreads();
  // Hillis-Steele inclusive scan over 256
#pragma unroll
  for (int dstep = 1; dstep < 256; dstep <<= 1) {
    int v = (tid >= dstep) ? sc[tid - dstep] : 0;
    __syncthreads();
    sc[tid] += v;
    __syncthreads();
  }
  int p = sc[tid] - cnt;
  for (int q = 0; q < cnt; q++) { kidx[p + q] = kl[q]; wval[p + q] = wl[q]; }
  __syncthreads();
  const int nnz = sc[255];
  for (int d = tid; d < DD; d += 256) {
    float re = 0.f, im = 0.f;
    for (int j = 0; j < nnz; j++) {
      int    k  = kidx[j];
      float2 w  = wval[j];
      float2 cs = tw[(k * d) & (DD - 1)];
      re += w.x * cs.x + w.y * cs.y;          // W * e^{-i th}
      im += w.y * cs.x - w.x * cs.y;
    }
    T[(size_t)o * DD + d] = make_float2(re, im);
  }
}

// ---------------------------------------------------------------------------
// TT[d][o] = bf16(Re T[o][d]); TT[d][1024+o] = bf16(Im T[o][d])  (transpose)
// ---------------------------------------------------------------------------
__global__ __launch_bounds__(256) void transpose_T_kernel(
    const float2* __restrict__ T, unsigned short* __restrict__ TT) {
  __shared__ float2 tile[64][65];
  const int o0 = blockIdx.x * 64, d0 = blockIdx.y * 64;
  for (int q = threadIdx.x; q < 64 * 64; q += 256) {
    int r = q >> 6, c = q & 63;                 // r: o, c: d
    tile[r][c] = T[(size_t)(o0 + r) * DD + d0 + c];
  }
  __syncthreads();
  for (int q = threadIdx.x; q < 64 * 64; q += 256) {
    int r = q >> 6, c = q & 63;                 // r: d, c: o
    float2 v = tile[c][r];
    TT[(size_t)(d0 + r) * 2048 + o0 + c]        = f2bf(v.x);
    TT[(size_t)(d0 + r) * 2048 + 1024 + o0 + c] = f2bf(v.y);
  }
}

// ---------------------------------------------------------------------------
// CS[m][o] = bf16(cos(2pi m o/D)); CS[m][1024+o] = bf16(-sin(2pi m o/D))
// ---------------------------------------------------------------------------
__global__ __launch_bounds__(256) void gen_CS_kernel(unsigned short* __restrict__ CS) {
  int idx = blockIdx.x * 256 + threadIdx.x;     // 1M = 1024x1024
  int m = idx >> 10, o = idx & 1023;
  float s, c;
  sincosf((TWO_PI / DD) * (float)((m * o) & (DD - 1)), &s, &c);
  CS[(size_t)m * 2048 + o]        = f2bf(c);
  CS[(size_t)m * 2048 + 1024 + o] = f2bf(-s);
}

// ---------------------------------------------------------------------------
// NT bf16 MFMA GEMM, 2-phase prefetch (T3-minimum): per K-step, issue the
// NEXT tile's staging FIRST, then ds_read+MFMA the CURRENT tile, then one
// vmcnt-drain barrier. Double-buffered LDS. Tile 128x(BN), 4 waves (2x2),
// 16x16x32 frags, BK=32.
// FUSEA: A is fp32 (X itself) — reg-staged global->reg, cvt->bf16, ds_write
//        (fuses the old convert_x kernel into the GEMM).
// MODE 0: fp32 out = acc*scale + bias[c].
// MODE 2: fp32 partials at Out + blockIdx.z*DD*DD, K-range [z*kLen, +kLen).
// ---------------------------------------------------------------------------
template <int LDK, int MODE, int BN, bool FUSEA>
__global__ __launch_bounds__(256) void mfma_nt_kernel(
    const void* __restrict__ Araw,          // (rows x LDK) bf16, or fp32 if FUSEA
    const unsigned short* __restrict__ B,   // (cols x LDK) bf16
    const float* __restrict__ bias,
    float* __restrict__ Out, float scale, int ldo, int kLen) {
  constexpr int NJ = BN / 32;               // b-frags per wave
  __shared__ __align__(16) unsigned short Asm[2][128 * 32];
  __shared__ __align__(16) unsigned short Bsm[2][BN * 32];
  const int tid  = threadIdx.x;
  const int wave = tid >> 6, lane = tid & 63;
  const int wr = wave >> 1, wc = wave & 1;
  const int row0 = blockIdx.y * 128;
  const int col0 = blockIdx.x * BN;
  const int kBeg = (MODE == 2) ? blockIdx.z * kLen : 0;
  const int kEnd = (MODE == 2) ? kBeg + kLen : LDK;
  const unsigned short* Abf = (const unsigned short*)Araw;
  const float*          Afp = (const float*)Araw;

  f32x4  acc[4][NJ] = {};
  float4 areg0, areg1, areg2, areg3;        // FUSEA staging (static names)

  for (int k0 = kBeg; k0 < kEnd; k0 += 32) {
    const bool first = (k0 == kBeg);
    const int  cur   = ((k0 - kBeg) >> 5) & 1;

    if (first) {
      // prologue: fill buffer 0
      if (FUSEA) {
#pragma unroll
        for (int is = 0; is < 2; is++) {
          int e = is * 256 + tid;
          int r = e >> 2, c = (e & 3) * 8;
          const float* ga = Afp + (size_t)(row0 + r) * LDK + kBeg + c;
          float4 a = *(const float4*)ga;
          float4 b2 = *(const float4*)(ga + 4);
          u16x8 v;
          v[0]=f2bf(a.x);  v[1]=f2bf(a.y);  v[2]=f2bf(a.z);  v[3]=f2bf(a.w);
          v[4]=f2bf(b2.x); v[5]=f2bf(b2.y); v[6]=f2bf(b2.z); v[7]=f2bf(b2.w);
          *(u16x8*)(Asm[0] + e * 8) = v;
        }
      } else {
#pragma unroll
        for (int is = 0; is < 2; is++) {
          int e = is * 256 + tid;
          int r = e >> 2, c = (e & 3) * 8;
          const unsigned short* ga = Abf + (size_t)(row0 + r) * LDK + kBeg + c;
          __builtin_amdgcn_global_load_lds((g_void*)ga,
              (l_void*)(Asm[0] + is * 2048 + wave * 512), 16, 0, 0);
        }
      }
#pragma unroll
      for (int is = 0; is < BN / 64; is++) {
        int e = is * 256 + tid;
        int r = e >> 2, c = (e & 3) * 8;
        const unsigned short* gb = B + (size_t)(col0 + r) * LDK + kBeg + c;
        __builtin_amdgcn_global_load_lds((g_void*)gb,
            (l_void*)(Bsm[0] + is * 2048 + wave * 512), 16, 0, 0);
      }
      __syncthreads();
    }

    const bool more = (k0 + 32 < kEnd);
    // ---- issue next tile's staging (before compute) ----
    if (more) {
      const int kn = k0 + 32, nxt = cur ^ 1;
      if (FUSEA) {
        {
          int e = tid;
          int r = e >> 2, c = (e & 3) * 8;
          const float* ga = Afp + (size_t)(row0 + r) * LDK + kn + c;
          areg0 = *(const float4*)ga;
          areg1 = *(const float4*)(ga + 4);
        }
        {
          int e = 256 + tid;
          int r = e >> 2, c = (e & 3) * 8;
          const float* ga = Afp + (size_t)(row0 + r) * LDK + kn + c;
          areg2 = *(const float4*)ga;
          areg3 = *(const float4*)(ga + 4);
        }
      } else {
#pragma unroll
        for (int is = 0; is < 2; is++) {
          int e = is * 256 + tid;
          int r = e >> 2, c = (e & 3) * 8;
          const unsigned short* ga = Abf + (size_t)(row0 + r) * LDK + kn + c;
          __builtin_amdgcn_global_load_lds((g_void*)ga,
              (l_void*)(Asm[nxt] + is * 2048 + wave * 512), 16, 0, 0);
        }
      }
#pragma unroll
      for (int is = 0; is < BN / 64; is++) {
        int e = is * 256 + tid;
        int r = e >> 2, c = (e & 3) * 8;
        const unsigned short* gb = B + (size_t)(col0 + r) * LDK + kn + c;
        __builtin_amdgcn_global_load_lds((g_void*)gb,
            (l_void*)(Bsm[nxt] + is * 2048 + wave * 512), 16, 0, 0);
      }
    }

    // ---- compute current tile ----
    {
      bf16x8 af[4], bfr[NJ];
#pragma unroll
      for (int i = 0; i < 4; i++) {
        int ra = wr * 64 + i * 16 + (lane & 15);
        af[i]  = *(const bf16x8*)&Asm[cur][ra * 32 + (lane >> 4) * 8];
      }
#pragma unroll
      for (int j = 0; j < NJ; j++) {
        int rb = wc * (BN / 2) + j * 16 + (lane & 15);
        bfr[j] = *(const bf16x8*)&Bsm[cur][rb * 32 + (lane >> 4) * 8];
      }
#pragma unroll
      for (int i = 0; i < 4; i++)
#pragma unroll
        for (int j = 0; j < NJ; j++)
          acc[i][j] = __builtin_amdgcn_mfma_f32_16x16x32_bf16(af[i], bfr[j], acc[i][j], 0, 0, 0);
    }

    // ---- FUSEA: convert staged regs and write into next LDS buffer ----
    if (FUSEA && more) {
      const int nxt = cur ^ 1;
      {
        u16x8 v;
        v[0]=f2bf(areg0.x); v[1]=f2bf(areg0.y); v[2]=f2bf(areg0.z); v[3]=f2bf(areg0.w);
        v[4]=f2bf(areg1.x); v[5]=f2bf(areg1.y); v[6]=f2bf(areg1.z); v[7]=f2bf(areg1.w);
        *(u16x8*)(Asm[nxt] + tid * 8) = v;
      }
      {
        u16x8 v;
        v[0]=f2bf(areg2.x); v[1]=f2bf(areg2.y); v[2]=f2bf(areg2.z); v[3]=f2bf(areg2.w);
        v[4]=f2bf(areg3.x); v[5]=f2bf(areg3.y); v[6]=f2bf(areg3.z); v[7]=f2bf(areg3.w);
        *(u16x8*)(Asm[nxt] + (256 + tid) * 8) = v;
      }
    }
    __syncthreads();   // drains vmcnt+lgkmcnt: next buffer ready
  }

  const int crow0 = row0 + wr * 64;
  const int ccol0 = col0 + wc * (BN / 2);
  if (MODE == 2) {
    float* O = Out + (size_t)blockIdx.z * DD * DD;
#pragma unroll
    for (int i = 0; i < 4; i++)
#pragma unroll
      for (int j = 0; j < NJ; j++) {
        int cc = ccol0 + j * 16 + (lane & 15);
#pragma unroll
        for (int v = 0; v < 4; v++) {
          int rr = crow0 + i * 16 + (lane >> 4) * 4 + v;
          O[(size_t)rr * ldo + cc] = acc[i][j][v];
        }
      }
  } else {
    float bv[NJ];
#pragma unroll
    for (int j = 0; j < NJ; j++)
      bv[j] = bias[ccol0 + j * 16 + (lane & 15)];
#pragma unroll
    for (int i = 0; i < 4; i++)
#pragma unroll
      for (int j = 0; j < NJ; j++) {
        int cc = ccol0 + j * 16 + (lane & 15);
#pragma unroll
        for (int v = 0; v < 4; v++) {
          int rr = crow0 + i * 16 + (lane >> 4) * 4 + v;
          Out[(size_t)rr * ldo + cc] = acc[i][j][v] * scale + bv[j];
        }
      }
  }
}

// ---------------------------------------------------------------------------
// Mb[i] = bf16( sum_z P_z[i] / D ),  i over 1M elements, x4 vec. NZ partials.
// ---------------------------------------------------------------------------
template <int NZ>
__global__ __launch_bounds__(256) void reduce_M_kernel(
    const float* __restrict__ P, unsigned short* __restrict__ Mb) {
  const size_t NE = (size_t)DD * DD;
  size_t i = ((size_t)blockIdx.x * 256 + threadIdx.x) * 4;
  float4 s = *(const float4*)(P + i);
#pragma unroll
  for (int z = 1; z < NZ; z++) {
    float4 p = *(const float4*)(P + z * NE + i);
    s.x += p.x; s.y += p.y; s.z += p.z; s.w += p.w;
  }
  const float inv = 1.0f / (float)DD;
  u16x4 v;
  v[0] = f2bf(s.x * inv); v[1] = f2bf(s.y * inv);
  v[2] = f2bf(s.z * inv); v[3] = f2bf(s.w * inv);
  *(u16x4*)(Mb + i) = v;
}

// ---------------------------------------------------------------------------
extern "C" void kernel_launch(void* const* d_in, const int* in_sizes, int n_in,
                              void* d_out, int out_size, void* d_ws, size_t ws_size,
                              hipStream_t stream) {
  const float* x    = (const float*)d_in[0];
  const float* wrp  = (const float*)d_in[1];
  const float* wip  = (const float*)d_in[2];
  const float* bias = (const float*)d_in[3];
  float*       y    = (float*)d_out;

  char* ws = (char*)d_ws;
  const size_t MB = 1024 * 1024;
  float2*         Wt = (float2*)(ws + 0);                // 8 MB (dead after build_T)
  float2*         T  = (float2*)(ws + 8  * MB);          // 8 MB (dead after transpose_T)
  unsigned short* TT = (unsigned short*)(ws + 16 * MB);  // 4 MB  [d][2048]
  unsigned short* CS = (unsigned short*)(ws + 20 * MB);  // 4 MB  [m][2048]
  unsigned short* Mb = (unsigned short*)(ws + 24 * MB);  // 2 MB  [m][d]
  float*          P  = (float*)(ws + 32 * MB);           // 32 MB (8 partials)

  transpose_W_kernel<<<dim3(16, 16), 256, 0, stream>>>(wrp, wip, Wt);
  build_T_kernel<<<DD, 256, 0, stream>>>(Wt, T);
  transpose_T_kernel<<<dim3(16, 16), 256, 0, stream>>>(T, TT);
  gen_CS_kernel<<<4096, 256, 0, stream>>>(CS);
  // P[z] = CS(1024x2048) . TT^T over K-chunk z of 256   (split-K x8)
  mfma_nt_kernel<2048, 2, 128, false><<<dim3(8, 8, 8), 256, 0, stream>>>(
      CS, TT, nullptr, P, 1.0f, DD, 256);
  reduce_M_kernel<8><<<DD * DD / (256 * 4), 256, 0, stream>>>(P, Mb);
  // Y = X(8192x1024 fp32, converted in-kernel) . Mb^T + bias -> fp32
  mfma_nt_kernel<1024, 0, 128, true><<<dim3(8, 64), 256, 0, stream>>>(
      x, Mb, bias, y, 1.0f, DD, 1024);
}

// Round 7
// 103.771 us; speedup vs baseline: 1.0592x; 1.0592x over previous
//
#include <hip/hip_runtime.h>
#include <hip/hip_bf16.h>
#include <math.h>

#define DD 1024          // D (in == out features)
#define BT 8192          // B*N tokens
#define TWO_PI 6.28318530717958647692f

typedef float f32x4 __attribute__((ext_vector_type(4)));
typedef short bf16x8 __attribute__((ext_vector_type(8)));
typedef unsigned short u16x8 __attribute__((ext_vector_type(8)));
typedef unsigned short u16x4 __attribute__((ext_vector_type(4)));
typedef const __attribute__((address_space(1))) void g_void;
typedef __attribute__((address_space(3))) void l_void;

__device__ __forceinline__ unsigned short f2bf(float f) {
  unsigned int u = __float_as_uint(f);
  unsigned int r = (u + 0x7FFFu + ((u >> 16) & 1u)) >> 16;   // RNE
  return (unsigned short)r;
}

// ---------------------------------------------------------------------------
// Transpose W (Wr,Wi fp32 (k,o)) -> Wt float2 (o,k), coalesced both sides.
// ---------------------------------------------------------------------------
__global__ __launch_bounds__(256) void transpose_W_kernel(
    const float* __restrict__ Wr, const float* __restrict__ Wi,
    float2* __restrict__ Wt) {
  __shared__ float tr[64][65];
  __shared__ float ti[64][65];
  const int k0 = blockIdx.y * 64, o0 = blockIdx.x * 64;
  for (int q = threadIdx.x; q < 64 * 64; q += 256) {
    int r = q >> 6, c = q & 63;                 // r: k, c: o
    tr[r][c] = Wr[(size_t)(k0 + r) * DD + o0 + c];
    ti[r][c] = Wi[(size_t)(k0 + r) * DD + o0 + c];
  }
  __syncthreads();
  for (int q = threadIdx.x; q < 64 * 64; q += 256) {
    int r = q >> 6, c = q & 63;                 // r: o, c: k
    Wt[(size_t)(o0 + r) * DD + k0 + c] = make_float2(tr[c][r], ti[c][r]);
  }
}

// ---------------------------------------------------------------------------
// T[o][d] = sum_k W[k][o] e^{-2pi i k d/D}. One block per o; compact nonzeros
// of row Wt[o][:] (coalesced) into LDS (parallel prefix), then twiddle table.
// ---------------------------------------------------------------------------
__global__ __launch_bounds__(256) void build_T_kernel(
    const float2* __restrict__ Wt, float2* __restrict__ T) {
  __shared__ float2 tw[DD];
  __shared__ int    kidx[64];
  __shared__ float2 wval[64];
  __shared__ int    sc[256];
  const int o = blockIdx.x, tid = threadIdx.x;

  for (int j = tid; j < DD; j += 256) {
    float s, c;
    sincosf((TWO_PI / DD) * (float)j, &s, &c);
    tw[j] = make_float2(c, s);
  }
  int cnt = 0;
  float2 wl[4];
  int    kl[4];
#pragma unroll
  for (int q = 0; q < 4; q++) {
    int k = tid + q * 256;
    float2 w = Wt[(size_t)o * DD + k];
    if (w.x != 0.f || w.y != 0.f) { wl[cnt] = w; kl[cnt] = k; cnt++; }
  }
  sc[tid] = cnt;
  __syncthreads();
  // Hillis-Steele inclusive scan over 256
#pragma unroll
  for (int dstep = 1; dstep < 256; dstep <<= 1) {
    int v = (tid >= dstep) ? sc[tid - dstep] : 0;
    __syncthreads();
    sc[tid] += v;
    __syncthreads();
  }
  int p = sc[tid] - cnt;
  for (int q = 0; q < cnt; q++) { kidx[p + q] = kl[q]; wval[p + q] = wl[q]; }
  __syncthreads();
  const int nnz = sc[255];
  for (int d = tid; d < DD; d += 256) {
    float re = 0.f, im = 0.f;
    for (int j = 0; j < nnz; j++) {
      int    k  = kidx[j];
      float2 w  = wval[j];
      float2 cs = tw[(k * d) & (DD - 1)];
      re += w.x * cs.x + w.y * cs.y;          // W * e^{-i th}
      im += w.y * cs.x - w.x * cs.y;
    }
    T[(size_t)o * DD + d] = make_float2(re, im);
  }
}

// ---------------------------------------------------------------------------
// TT[d][o] = bf16(Re T[o][d]); TT[d][1024+o] = bf16(Im T[o][d])  (transpose)
// ---------------------------------------------------------------------------
__global__ __launch_bounds__(256) void transpose_T_kernel(
    const float2* __restrict__ T, unsigned short* __restrict__ TT) {
  __shared__ float2 tile[64][65];
  const int o0 = blockIdx.x * 64, d0 = blockIdx.y * 64;
  for (int q = threadIdx.x; q < 64 * 64; q += 256) {
    int r = q >> 6, c = q & 63;                 // r: o, c: d
    tile[r][c] = T[(size_t)(o0 + r) * DD + d0 + c];
  }
  __syncthreads();
  for (int q = threadIdx.x; q < 64 * 64; q += 256) {
    int r = q >> 6, c = q & 63;                 // r: d, c: o
    float2 v = tile[c][r];
    TT[(size_t)(d0 + r) * 2048 + o0 + c]        = f2bf(v.x);
    TT[(size_t)(d0 + r) * 2048 + 1024 + o0 + c] = f2bf(v.y);
  }
}

// ---------------------------------------------------------------------------
// x fp32 -> bf16 (8 elems/thread)
// ---------------------------------------------------------------------------
__global__ __launch_bounds__(256) void convert_x_kernel(
    const float* __restrict__ X, unsigned short* __restrict__ Xb) {
  size_t i = (size_t)blockIdx.x * 256 + threadIdx.x;   // chunk of 8
  const float4* p = (const float4*)(X + i * 8);
  float4 a = p[0], b = p[1];
  u16x8 v;
  v[0] = f2bf(a.x); v[1] = f2bf(a.y); v[2] = f2bf(a.z); v[3] = f2bf(a.w);
  v[4] = f2bf(b.x); v[5] = f2bf(b.y); v[6] = f2bf(b.z); v[7] = f2bf(b.w);
  *(u16x8*)(Xb + i * 8) = v;
}

// ---------------------------------------------------------------------------
// build_M: P_z[m][d] = sum_{k in z-chunk} CS(m,k) * TT[d][k]
// where CS(m,k) = cos(2pi(m*o mod D)/D) for k=o<1024, -sin(...) for k>=1024.
// A-tile (twiddles) is GENERATED in-register (__sincosf) + ds_write — no CS
// array, no gen_CS kernel. B staged via global_load_lds. 128x128 tile, BK=32,
// 4 waves, 4x4 frags, split-K x4 (blockIdx.z), R3-proven 2-barrier loop.
// ---------------------------------------------------------------------------
__global__ __launch_bounds__(256) void build_M_kernel(
    const unsigned short* __restrict__ B,   // TT (1024 x 2048) bf16
    float* __restrict__ P, int kLen) {
  __shared__ __align__(16) unsigned short Asm[128 * 32];
  __shared__ __align__(16) unsigned short Bsm[128 * 32];
  const int tid  = threadIdx.x;
  const int wave = tid >> 6, lane = tid & 63;
  const int wr = wave >> 1, wc = wave & 1;
  const int row0 = blockIdx.y * 128;     // m
  const int col0 = blockIdx.x * 128;     // d
  const int kBeg = blockIdx.z * kLen;

  f32x4 acc[4][4] = {};

  for (int k0 = kBeg; k0 < kBeg + kLen; k0 += 32) {
    __syncthreads();
    // B: global_load_lds
#pragma unroll
    for (int is = 0; is < 2; is++) {
      int e = is * 256 + tid;
      int r = e >> 2, c = (e & 3) * 8;
      const unsigned short* gb = B + (size_t)(col0 + r) * 2048 + k0 + c;
      __builtin_amdgcn_global_load_lds((g_void*)gb,
          (l_void*)(Bsm + is * 2048 + wave * 512), 16, 0, 0);
    }
    // A: generate twiddles in-register, ds_write_b128
#pragma unroll
    for (int is = 0; is < 2; is++) {
      int e = is * 256 + tid;
      int r = e >> 2, c = (e & 3) * 8;
      int m = row0 + r;
      u16x8 v;
#pragma unroll
      for (int q = 0; q < 8; q++) {
        int kg   = k0 + c + q;
        int o    = kg & (DD - 1);
        int idx  = (m * o) & (DD - 1);
        float s, cc;
        __sincosf((TWO_PI / DD) * (float)idx, &s, &cc);
        v[q] = f2bf((kg < DD) ? cc : -s);
      }
      *(u16x8*)(Asm + e * 8) = v;
    }
    __syncthreads();

    bf16x8 af[4], bfr[4];
#pragma unroll
    for (int i = 0; i < 4; i++) {
      int ra = wr * 64 + i * 16 + (lane & 15);
      af[i]  = *(const bf16x8*)&Asm[ra * 32 + (lane >> 4) * 8];
      int rb = wc * 64 + i * 16 + (lane & 15);
      bfr[i] = *(const bf16x8*)&Bsm[rb * 32 + (lane >> 4) * 8];
    }
#pragma unroll
    for (int i = 0; i < 4; i++)
#pragma unroll
      for (int j = 0; j < 4; j++)
        acc[i][j] = __builtin_amdgcn_mfma_f32_16x16x32_bf16(af[i], bfr[j], acc[i][j], 0, 0, 0);
  }

  const int crow0 = row0 + wr * 64;
  const int ccol0 = col0 + wc * 64;
  float* O = P + (size_t)blockIdx.z * DD * DD;
#pragma unroll
  for (int i = 0; i < 4; i++)
#pragma unroll
    for (int j = 0; j < 4; j++) {
      int cc = ccol0 + j * 16 + (lane & 15);
#pragma unroll
      for (int v = 0; v < 4; v++) {
        int rr = crow0 + i * 16 + (lane >> 4) * 4 + v;
        O[(size_t)rr * DD + cc] = acc[i][j][v];
      }
    }
}

// ---------------------------------------------------------------------------
// Mb[i] = bf16( sum_z P_z[i] / D ),  x4 vectorized, NZ partials.
// ---------------------------------------------------------------------------
template <int NZ>
__global__ __launch_bounds__(256) void reduce_M_kernel(
    const float* __restrict__ P, unsigned short* __restrict__ Mb) {
  const size_t NE = (size_t)DD * DD;
  size_t i = ((size_t)blockIdx.x * 256 + threadIdx.x) * 4;
  float4 s = *(const float4*)(P + i);
#pragma unroll
  for (int z = 1; z < NZ; z++) {
    float4 p = *(const float4*)(P + z * NE + i);
    s.x += p.x; s.y += p.y; s.z += p.z; s.w += p.w;
  }
  const float inv = 1.0f / (float)DD;
  u16x4 v;
  v[0] = f2bf(s.x * inv); v[1] = f2bf(s.y * inv);
  v[2] = f2bf(s.z * inv); v[3] = f2bf(s.w * inv);
  *(u16x4*)(Mb + i) = v;
}

// ---------------------------------------------------------------------------
// gemm_y: Y[t][m] = sum_k Xb[t][k]*Mb[m][k] + bias[m]  (NT, bf16 MFMA)
// In-block split-K: 512 threads = 8 waves; waves 0-3 (kw=0) do k in [0,512),
// waves 4-7 (kw=1) do [512,1024) on the SAME 128x128 tile (R3-proven
// 2-barrier BK=32 loop per half). Doubles waves/CU (8->16) without changing
// tile shape or fetch pattern. Chunked LDS reduction (4 rounds, reuses
// staging LDS) merges the two half-K accumulators; kw=0 adds bias & stores.
// ---------------------------------------------------------------------------
__global__ __launch_bounds__(512) void gemm_y_kernel(
    const unsigned short* __restrict__ Xb,   // (8192 x 1024) bf16
    const unsigned short* __restrict__ Mb,   // (1024 x 1024) bf16
    const float* __restrict__ bias,
    float* __restrict__ Y) {
  __shared__ __align__(16) unsigned short Asm[2][128 * 32];
  __shared__ __align__(16) unsigned short Bsm[2][128 * 32];
  const int tid  = threadIdx.x;
  const int wave = tid >> 6, lane = tid & 63;
  const int kw   = wave >> 2;              // k-group: 0 or 1
  const int w4   = wave & 3;               // wave within k-group
  const int wr   = w4 >> 1, wc = w4 & 1;
  const int t256 = tid & 255;              // thread within k-group
  const int row0 = blockIdx.y * 128;
  const int col0 = blockIdx.x * 128;
  const int kBeg = kw * 512;

  f32x4 acc[4][4] = {};

  for (int k0 = kBeg; k0 < kBeg + 512; k0 += 32) {
    __syncthreads();
#pragma unroll
    for (int is = 0; is < 2; is++) {
      int e = is * 256 + t256;
      int r = e >> 2, c = (e & 3) * 8;
      const unsigned short* ga = Xb + (size_t)(row0 + r) * DD + k0 + c;
      const unsigned short* gb = Mb + (size_t)(col0 + r) * DD + k0 + c;
      __builtin_amdgcn_global_load_lds((g_void*)ga,
          (l_void*)(Asm[kw] + is * 2048 + w4 * 512), 16, 0, 0);
      __builtin_amdgcn_global_load_lds((g_void*)gb,
          (l_void*)(Bsm[kw] + is * 2048 + w4 * 512), 16, 0, 0);
    }
    __syncthreads();

    bf16x8 af[4], bfr[4];
#pragma unroll
    for (int i = 0; i < 4; i++) {
      int ra = wr * 64 + i * 16 + (lane & 15);
      af[i]  = *(const bf16x8*)&Asm[kw][ra * 32 + (lane >> 4) * 8];
      int rb = wc * 64 + i * 16 + (lane & 15);
      bfr[i] = *(const bf16x8*)&Bsm[kw][rb * 32 + (lane >> 4) * 8];
    }
#pragma unroll
    for (int i = 0; i < 4; i++)
#pragma unroll
      for (int j = 0; j < 4; j++)
        acc[i][j] = __builtin_amdgcn_mfma_f32_16x16x32_bf16(af[i], bfr[j], acc[i][j], 0, 0, 0);
  }

  // ---- merge kw=1 into kw=0 via LDS (4 rounds of 16 KB), store ----
  const int crow0 = row0 + wr * 64;
  const int ccol0 = col0 + wc * 64;
  float bv[4];
#pragma unroll
  for (int j = 0; j < 4; j++)
    bv[j] = bias[ccol0 + j * 16 + (lane & 15)];

  float* red = (float*)Asm;   // 16 KB scratch (Asm[0..1])
#pragma unroll
  for (int i = 0; i < 4; i++) {
    __syncthreads();
    if (kw == 1) {
      float* dst = red + (w4 * 64 + lane) * 16;
#pragma unroll
      for (int j = 0; j < 4; j++) *(f32x4*)(dst + j * 4) = acc[i][j];
    }
    __syncthreads();
    if (kw == 0) {
      const float* src = red + (w4 * 64 + lane) * 16;
#pragma unroll
      for (int j = 0; j < 4; j++) {
        f32x4 oth = *(const f32x4*)(src + j * 4);
        int cc = ccol0 + j * 16 + (lane & 15);
#pragma unroll
        for (int v = 0; v < 4; v++) {
          int rr = crow0 + i * 16 + (lane >> 4) * 4 + v;
          Y[(size_t)rr * DD + cc] = acc[i][j][v] + oth[v] + bv[j];
        }
      }
    }
  }
}

// ---------------------------------------------------------------------------
extern "C" void kernel_launch(void* const* d_in, const int* in_sizes, int n_in,
                              void* d_out, int out_size, void* d_ws, size_t ws_size,
                              hipStream_t stream) {
  const float* x    = (const float*)d_in[0];
  const float* wrp  = (const float*)d_in[1];
  const float* wip  = (const float*)d_in[2];
  const float* bias = (const float*)d_in[3];
  float*       y    = (float*)d_out;

  char* ws = (char*)d_ws;
  const size_t MB = 1024 * 1024;
  float2*         Wt = (float2*)(ws + 0);                // 8 MB (dead after build_T)
  float2*         T  = (float2*)(ws + 8  * MB);          // 8 MB (dead after transpose_T)
  unsigned short* TT = (unsigned short*)(ws + 16 * MB);  // 4 MB  [d][2048]
  unsigned short* Mb = (unsigned short*)(ws + 24 * MB);  // 2 MB  [m][d]
  float*          P  = (float*)(ws + 32 * MB);           // 16 MB (4 partials)
  unsigned short* Xb = (unsigned short*)(ws + 0);        // 16 MB (reuses Wt/T)

  transpose_W_kernel<<<dim3(16, 16), 256, 0, stream>>>(wrp, wip, Wt);
  build_T_kernel<<<DD, 256, 0, stream>>>(Wt, T);
  transpose_T_kernel<<<dim3(16, 16), 256, 0, stream>>>(T, TT);
  // P[z] = CS(generated) . TT^T over K-chunk z of 512   (split-K x4)
  build_M_kernel<<<dim3(8, 8, 4), 256, 0, stream>>>(TT, P, 512);
  reduce_M_kernel<4><<<DD * DD / (256 * 4), 256, 0, stream>>>(P, Mb);
  convert_x_kernel<<<4096, 256, 0, stream>>>(x, Xb);
  // Y = Xb . Mb^T + bias (in-block split-K x2, 8 waves)
  gemm_y_kernel<<<dim3(8, 64), 512, 0, stream>>>(Xb, Mb, bias, y);
}

// Round 8
// 102.626 us; speedup vs baseline: 1.0710x; 1.0112x over previous
//
#include <hip/hip_runtime.h>
#include <hip/hip_bf16.h>
#include <math.h>

#define DD 1024          // D (in == out features)
#define BT 8192          // B*N tokens
#define TWO_PI 6.28318530717958647692f

typedef float f32x4 __attribute__((ext_vector_type(4)));
typedef short bf16x8 __attribute__((ext_vector_type(8)));
typedef unsigned short u16x8 __attribute__((ext_vector_type(8)));
typedef unsigned short u16x4 __attribute__((ext_vector_type(4)));
typedef const __attribute__((address_space(1))) void g_void;
typedef __attribute__((address_space(3))) void l_void;

__device__ __forceinline__ unsigned short f2bf(float f) {
  unsigned int u = __float_as_uint(f);
  unsigned int r = (u + 0x7FFFu + ((u >> 16) & 1u)) >> 16;   // RNE
  return (unsigned short)r;
}

// ---------------------------------------------------------------------------
// Transpose W (Wr,Wi fp32 (k,o)) -> Wt float2 (o,k), coalesced both sides.
// ---------------------------------------------------------------------------
__global__ __launch_bounds__(256) void transpose_W_kernel(
    const float* __restrict__ Wr, const float* __restrict__ Wi,
    float2* __restrict__ Wt) {
  __shared__ float tr[64][65];
  __shared__ float ti[64][65];
  const int k0 = blockIdx.y * 64, o0 = blockIdx.x * 64;
  for (int q = threadIdx.x; q < 64 * 64; q += 256) {
    int r = q >> 6, c = q & 63;                 // r: k, c: o
    tr[r][c] = Wr[(size_t)(k0 + r) * DD + o0 + c];
    ti[r][c] = Wi[(size_t)(k0 + r) * DD + o0 + c];
  }
  __syncthreads();
  for (int q = threadIdx.x; q < 64 * 64; q += 256) {
    int r = q >> 6, c = q & 63;                 // r: o, c: k
    Wt[(size_t)(o0 + r) * DD + k0 + c] = make_float2(tr[c][r], ti[c][r]);
  }
}

// ---------------------------------------------------------------------------
// T[o][d] = sum_k W[k][o] e^{-2pi i k d/D}. One block per o; compact nonzeros
// of row Wt[o][:] (coalesced) into LDS (parallel prefix), then twiddle table.
// ---------------------------------------------------------------------------
__global__ __launch_bounds__(256) void build_T_kernel(
    const float2* __restrict__ Wt, float2* __restrict__ T) {
  __shared__ float2 tw[DD];
  __shared__ int    kidx[64];
  __shared__ float2 wval[64];
  __shared__ int    sc[256];
  const int o = blockIdx.x, tid = threadIdx.x;

  for (int j = tid; j < DD; j += 256) {
    float s, c;
    sincosf((TWO_PI / DD) * (float)j, &s, &c);
    tw[j] = make_float2(c, s);
  }
  int cnt = 0;
  float2 wl[4];
  int    kl[4];
#pragma unroll
  for (int q = 0; q < 4; q++) {
    int k = tid + q * 256;
    float2 w = Wt[(size_t)o * DD + k];
    if (w.x != 0.f || w.y != 0.f) { wl[cnt] = w; kl[cnt] = k; cnt++; }
  }
  sc[tid] = cnt;
  __syncthreads();
  // Hillis-Steele inclusive scan over 256
#pragma unroll
  for (int dstep = 1; dstep < 256; dstep <<= 1) {
    int v = (tid >= dstep) ? sc[tid - dstep] : 0;
    __syncthreads();
    sc[tid] += v;
    __syncthreads();
  }
  int p = sc[tid] - cnt;
  for (int q = 0; q < cnt; q++) { kidx[p + q] = kl[q]; wval[p + q] = wl[q]; }
  __syncthreads();
  const int nnz = sc[255];
  for (int d = tid; d < DD; d += 256) {
    float re = 0.f, im = 0.f;
    for (int j = 0; j < nnz; j++) {
      int    k  = kidx[j];
      float2 w  = wval[j];
      float2 cs = tw[(k * d) & (DD - 1)];
      re += w.x * cs.x + w.y * cs.y;          // W * e^{-i th}
      im += w.y * cs.x - w.x * cs.y;
    }
    T[(size_t)o * DD + d] = make_float2(re, im);
  }
}

// ---------------------------------------------------------------------------
// TT[d][o] = bf16(Re T[o][d]); TT[d][1024+o] = bf16(Im T[o][d])  (transpose)
// ---------------------------------------------------------------------------
__global__ __launch_bounds__(256) void transpose_T_kernel(
    const float2* __restrict__ T, unsigned short* __restrict__ TT) {
  __shared__ float2 tile[64][65];
  const int o0 = blockIdx.x * 64, d0 = blockIdx.y * 64;
  for (int q = threadIdx.x; q < 64 * 64; q += 256) {
    int r = q >> 6, c = q & 63;                 // r: o, c: d
    tile[r][c] = T[(size_t)(o0 + r) * DD + d0 + c];
  }
  __syncthreads();
  for (int q = threadIdx.x; q < 64 * 64; q += 256) {
    int r = q >> 6, c = q & 63;                 // r: d, c: o
    float2 v = tile[c][r];
    TT[(size_t)(d0 + r) * 2048 + o0 + c]        = f2bf(v.x);
    TT[(size_t)(d0 + r) * 2048 + 1024 + o0 + c] = f2bf(v.y);
  }
}

// ---------------------------------------------------------------------------
// x fp32 -> bf16 (8 elems/thread)
// ---------------------------------------------------------------------------
__global__ __launch_bounds__(256) void convert_x_kernel(
    const float* __restrict__ X, unsigned short* __restrict__ Xb) {
  size_t i = (size_t)blockIdx.x * 256 + threadIdx.x;   // chunk of 8
  const float4* p = (const float4*)(X + i * 8);
  float4 a = p[0], b = p[1];
  u16x8 v;
  v[0] = f2bf(a.x); v[1] = f2bf(a.y); v[2] = f2bf(a.z); v[3] = f2bf(a.w);
  v[4] = f2bf(b.x); v[5] = f2bf(b.y); v[6] = f2bf(b.z); v[7] = f2bf(b.w);
  *(u16x8*)(Xb + i * 8) = v;
}

// ---------------------------------------------------------------------------
// build_M: P_z[m][d] = sum_{k in z-chunk} CS(m,k) * TT[d][k]
// A-tile (twiddles) generated in-register (__sincosf) + ds_write. B staged
// via global_load_lds. 128x128 tile, BK=32, 4 waves, split-K x4, 2-barrier.
// ---------------------------------------------------------------------------
__global__ __launch_bounds__(256) void build_M_kernel(
    const unsigned short* __restrict__ B,   // TT (1024 x 2048) bf16
    float* __restrict__ P, int kLen) {
  __shared__ __align__(16) unsigned short Asm[128 * 32];
  __shared__ __align__(16) unsigned short Bsm[128 * 32];
  const int tid  = threadIdx.x;
  const int wave = tid >> 6, lane = tid & 63;
  const int wr = wave >> 1, wc = wave & 1;
  const int row0 = blockIdx.y * 128;     // m
  const int col0 = blockIdx.x * 128;     // d
  const int kBeg = blockIdx.z * kLen;

  f32x4 acc[4][4] = {};

  for (int k0 = kBeg; k0 < kBeg + kLen; k0 += 32) {
    __syncthreads();
#pragma unroll
    for (int is = 0; is < 2; is++) {
      int e = is * 256 + tid;
      int r = e >> 2, c = (e & 3) * 8;
      const unsigned short* gb = B + (size_t)(col0 + r) * 2048 + k0 + c;
      __builtin_amdgcn_global_load_lds((g_void*)gb,
          (l_void*)(Bsm + is * 2048 + wave * 512), 16, 0, 0);
    }
#pragma unroll
    for (int is = 0; is < 2; is++) {
      int e = is * 256 + tid;
      int r = e >> 2, c = (e & 3) * 8;
      int m = row0 + r;
      u16x8 v;
#pragma unroll
      for (int q = 0; q < 8; q++) {
        int kg   = k0 + c + q;
        int o    = kg & (DD - 1);
        int idx  = (m * o) & (DD - 1);
        float s, cc;
        __sincosf((TWO_PI / DD) * (float)idx, &s, &cc);
        v[q] = f2bf((kg < DD) ? cc : -s);
      }
      *(u16x8*)(Asm + e * 8) = v;
    }
    __syncthreads();

    bf16x8 af[4], bfr[4];
#pragma unroll
    for (int i = 0; i < 4; i++) {
      int ra = wr * 64 + i * 16 + (lane & 15);
      af[i]  = *(const bf16x8*)&Asm[ra * 32 + (lane >> 4) * 8];
      int rb = wc * 64 + i * 16 + (lane & 15);
      bfr[i] = *(const bf16x8*)&Bsm[rb * 32 + (lane >> 4) * 8];
    }
#pragma unroll
    for (int i = 0; i < 4; i++)
#pragma unroll
      for (int j = 0; j < 4; j++)
        acc[i][j] = __builtin_amdgcn_mfma_f32_16x16x32_bf16(af[i], bfr[j], acc[i][j], 0, 0, 0);
  }

  const int crow0 = row0 + wr * 64;
  const int ccol0 = col0 + wc * 64;
  float* O = P + (size_t)blockIdx.z * DD * DD;
#pragma unroll
  for (int i = 0; i < 4; i++)
#pragma unroll
    for (int j = 0; j < 4; j++) {
      int cc = ccol0 + j * 16 + (lane & 15);
#pragma unroll
      for (int v = 0; v < 4; v++) {
        int rr = crow0 + i * 16 + (lane >> 4) * 4 + v;
        O[(size_t)rr * DD + cc] = acc[i][j][v];
      }
    }
}

// ---------------------------------------------------------------------------
// Mb[i] = bf16( sum_z P_z[i] / D ),  x4 vectorized, NZ partials.
// ---------------------------------------------------------------------------
template <int NZ>
__global__ __launch_bounds__(256) void reduce_M_kernel(
    const float* __restrict__ P, unsigned short* __restrict__ Mb) {
  const size_t NE = (size_t)DD * DD;
  size_t i = ((size_t)blockIdx.x * 256 + threadIdx.x) * 4;
  float4 s = *(const float4*)(P + i);
#pragma unroll
  for (int z = 1; z < NZ; z++) {
    float4 p = *(const float4*)(P + z * NE + i);
    s.x += p.x; s.y += p.y; s.z += p.z; s.w += p.w;
  }
  const float inv = 1.0f / (float)DD;
  u16x4 v;
  v[0] = f2bf(s.x * inv); v[1] = f2bf(s.y * inv);
  v[2] = f2bf(s.z * inv); v[3] = f2bf(s.w * inv);
  *(u16x4*)(Mb + i) = v;
}

// ---------------------------------------------------------------------------
// gemm_y: Y[t][m] = sum_k Xb[t][k]*Mb[m][k] + bias[m]  (NT, bf16 MFMA)
// 128x128 tile, 4 waves, BK=32, 3-deep counted-vmcnt pipeline:
//   per K-step: s_waitcnt vmcnt(4) -> s_barrier -> issue stage(t+2) ->
//   ds_read+MFMA(t). Loads stay in flight across barriers (never vmcnt(0)
//   in-loop). Race-safety: every ds_read of buf t is consumed by an MFMA
//   (compiler lgkmcnt) before this wave reaches the next barrier, so
//   stage(t+2) overwriting buf (t-1)%3 after the barrier is safe.
// LDS XOR swizzle (both-sides, rule #21): linear global_load_lds dest,
//   inverse-permuted global source col-block, XOR'd ds_read index:
//   cb' = cb ^ ((row>>1)&3). 8-way bank conflict -> 2-way (free).
// ---------------------------------------------------------------------------
__global__ __launch_bounds__(256) void gemm_y_kernel(
    const unsigned short* __restrict__ Xb,   // (8192 x 1024) bf16
    const unsigned short* __restrict__ Mb,   // (1024 x 1024) bf16
    const float* __restrict__ bias,
    float* __restrict__ Y) {
  __shared__ __align__(16) unsigned short Asm[3][128 * 32];
  __shared__ __align__(16) unsigned short Bsm[3][128 * 32];
  const int tid  = threadIdx.x;
  const int wave = tid >> 6, lane = tid & 63;
  const int wr = wave >> 1, wc = wave & 1;
  const int row0 = blockIdx.y * 128;
  const int col0 = blockIdx.x * 128;
  const int NT = DD / 32;                  // 32 K-steps

#define STAGE_Y(buf, kk)                                                     \
  {                                                                          \
    _Pragma("unroll")                                                        \
    for (int is = 0; is < 2; is++) {                                         \
      int e  = is * 256 + tid;                                               \
      int r  = e >> 2;                                                       \
      int cb = ((e & 3) ^ ((e >> 3) & 3)) * 8;  /* inverse swizzle on src */ \
      const unsigned short* ga = Xb + (size_t)(row0 + r) * DD + (kk) + cb;   \
      const unsigned short* gb = Mb + (size_t)(col0 + r) * DD + (kk) + cb;   \
      __builtin_amdgcn_global_load_lds((g_void*)ga,                          \
          (l_void*)(Asm[buf] + is * 2048 + wave * 512), 16, 0, 0);           \
      __builtin_amdgcn_global_load_lds((g_void*)gb,                          \
          (l_void*)(Bsm[buf] + is * 2048 + wave * 512), 16, 0, 0);           \
    }                                                                        \
  }

  f32x4 acc[4][4] = {};

  STAGE_Y(0, 0);
  STAGE_Y(1, 32);

  int cur = 0;
  for (int t = 0; t < NT; ++t) {
    if (t < NT - 1) {
      asm volatile("s_waitcnt vmcnt(4)" ::: "memory");
    } else {
      asm volatile("s_waitcnt vmcnt(0)" ::: "memory");
    }
    __builtin_amdgcn_s_barrier();
    __builtin_amdgcn_sched_barrier(0);

    if (t < NT - 2) {
      int nb = cur + 2; if (nb >= 3) nb -= 3;
      STAGE_Y(nb, (t + 2) * 32);
    }

    bf16x8 af[4], bfr[4];
#pragma unroll
    for (int i = 0; i < 4; i++) {
      int ra = wr * 64 + i * 16 + (lane & 15);
      int ca = ((lane >> 4) ^ ((ra >> 1) & 3)) * 8;
      af[i]  = *(const bf16x8*)&Asm[cur][ra * 32 + ca];
      int rb = wc * 64 + i * 16 + (lane & 15);
      int cb = ((lane >> 4) ^ ((rb >> 1) & 3)) * 8;
      bfr[i] = *(const bf16x8*)&Bsm[cur][rb * 32 + cb];
    }
#pragma unroll
    for (int i = 0; i < 4; i++)
#pragma unroll
      for (int j = 0; j < 4; j++)
        acc[i][j] = __builtin_amdgcn_mfma_f32_16x16x32_bf16(af[i], bfr[j], acc[i][j], 0, 0, 0);

    cur = cur + 1 == 3 ? 0 : cur + 1;
  }
#undef STAGE_Y

  const int crow0 = row0 + wr * 64;
  const int ccol0 = col0 + wc * 64;
  float bv[4];
#pragma unroll
  for (int j = 0; j < 4; j++)
    bv[j] = bias[ccol0 + j * 16 + (lane & 15)];
#pragma unroll
  for (int i = 0; i < 4; i++)
#pragma unroll
    for (int j = 0; j < 4; j++) {
      int cc = ccol0 + j * 16 + (lane & 15);
#pragma unroll
      for (int v = 0; v < 4; v++) {
        int rr = crow0 + i * 16 + (lane >> 4) * 4 + v;
        Y[(size_t)rr * DD + cc] = acc[i][j][v] + bv[j];
      }
    }
}

// ---------------------------------------------------------------------------
extern "C" void kernel_launch(void* const* d_in, const int* in_sizes, int n_in,
                              void* d_out, int out_size, void* d_ws, size_t ws_size,
                              hipStream_t stream) {
  const float* x    = (const float*)d_in[0];
  const float* wrp  = (const float*)d_in[1];
  const float* wip  = (const float*)d_in[2];
  const float* bias = (const float*)d_in[3];
  float*       y    = (float*)d_out;

  char* ws = (char*)d_ws;
  const size_t MB = 1024 * 1024;
  float2*         Wt = (float2*)(ws + 0);                // 8 MB (dead after build_T)
  float2*         T  = (float2*)(ws + 8  * MB);          // 8 MB (dead after transpose_T)
  unsigned short* TT = (unsigned short*)(ws + 16 * MB);  // 4 MB  [d][2048]
  unsigned short* Mb = (unsigned short*)(ws + 24 * MB);  // 2 MB  [m][d]
  float*          P  = (float*)(ws + 32 * MB);           // 16 MB (4 partials)
  unsigned short* Xb = (unsigned short*)(ws + 0);        // 16 MB (reuses Wt/T)

  transpose_W_kernel<<<dim3(16, 16), 256, 0, stream>>>(wrp, wip, Wt);
  build_T_kernel<<<DD, 256, 0, stream>>>(Wt, T);
  transpose_T_kernel<<<dim3(16, 16), 256, 0, stream>>>(T, TT);
  // P[z] = CS(generated) . TT^T over K-chunk z of 512   (split-K x4)
  build_M_kernel<<<dim3(8, 8, 4), 256, 0, stream>>>(TT, P, 512);
  reduce_M_kernel<4><<<DD * DD / (256 * 4), 256, 0, stream>>>(P, Mb);
  convert_x_kernel<<<4096, 256, 0, stream>>>(x, Xb);
  // Y = Xb . Mb^T + bias (3-deep counted-vmcnt pipeline)
  gemm_y_kernel<<<dim3(8, 64), 256, 0, stream>>>(Xb, Mb, bias, y);
}

// Round 9
// 102.006 us; speedup vs baseline: 1.0775x; 1.0061x over previous
//
#include <hip/hip_runtime.h>
#include <hip/hip_bf16.h>
#include <math.h>

#define DD 1024          // D (in == out features)
#define BT 8192          // B*N tokens
#define TWO_PI 6.28318530717958647692f

typedef float f32x4 __attribute__((ext_vector_type(4)));
typedef short bf16x8 __attribute__((ext_vector_type(8)));
typedef unsigned short u16x8 __attribute__((ext_vector_type(8)));
typedef unsigned short u16x4 __attribute__((ext_vector_type(4)));
typedef const __attribute__((address_space(1))) void g_void;
typedef __attribute__((address_space(3))) void l_void;

__device__ __forceinline__ unsigned short f2bf(float f) {
  unsigned int u = __float_as_uint(f);
  unsigned int r = (u + 0x7FFFu + ((u >> 16) & 1u)) >> 16;   // RNE
  return (unsigned short)r;
}

// ---------------------------------------------------------------------------
// Transpose W (Wr,Wi fp32 (k,o)) -> Wt float2 (o,k), coalesced both sides.
// ---------------------------------------------------------------------------
__global__ __launch_bounds__(256) void transpose_W_kernel(
    const float* __restrict__ Wr, const float* __restrict__ Wi,
    float2* __restrict__ Wt) {
  __shared__ float tr[64][65];
  __shared__ float ti[64][65];
  const int k0 = blockIdx.y * 64, o0 = blockIdx.x * 64;
  for (int q = threadIdx.x; q < 64 * 64; q += 256) {
    int r = q >> 6, c = q & 63;                 // r: k, c: o
    tr[r][c] = Wr[(size_t)(k0 + r) * DD + o0 + c];
    ti[r][c] = Wi[(size_t)(k0 + r) * DD + o0 + c];
  }
  __syncthreads();
  for (int q = threadIdx.x; q < 64 * 64; q += 256) {
    int r = q >> 6, c = q & 63;                 // r: o, c: k
    Wt[(size_t)(o0 + r) * DD + k0 + c] = make_float2(tr[c][r], ti[c][r]);
  }
}

// ---------------------------------------------------------------------------
// T[o][d] = sum_k W[k][o] e^{-2pi i k d/D}. One block per o; compact nonzeros
// of row Wt[o][:] (coalesced) into LDS (parallel prefix), then twiddle table.
// ---------------------------------------------------------------------------
__global__ __launch_bounds__(256) void build_T_kernel(
    const float2* __restrict__ Wt, float2* __restrict__ T) {
  __shared__ float2 tw[DD];
  __shared__ int    kidx[64];
  __shared__ float2 wval[64];
  __shared__ int    sc[256];
  const int o = blockIdx.x, tid = threadIdx.x;

  for (int j = tid; j < DD; j += 256) {
    float s, c;
    sincosf((TWO_PI / DD) * (float)j, &s, &c);
    tw[j] = make_float2(c, s);
  }
  int cnt = 0;
  float2 wl[4];
  int    kl[4];
#pragma unroll
  for (int q = 0; q < 4; q++) {
    int k = tid + q * 256;
    float2 w = Wt[(size_t)o * DD + k];
    if (w.x != 0.f || w.y != 0.f) { wl[cnt] = w; kl[cnt] = k; cnt++; }
  }
  sc[tid] = cnt;
  __syncthreads();
  // Hillis-Steele inclusive scan over 256
#pragma unroll
  for (int dstep = 1; dstep < 256; dstep <<= 1) {
    int v = (tid >= dstep) ? sc[tid - dstep] : 0;
    __syncthreads();
    sc[tid] += v;
    __syncthreads();
  }
  int p = sc[tid] - cnt;
  for (int q = 0; q < cnt; q++) { kidx[p + q] = kl[q]; wval[p + q] = wl[q]; }
  __syncthreads();
  const int nnz = sc[255];
  for (int d = tid; d < DD; d += 256) {
    float re = 0.f, im = 0.f;
    for (int j = 0; j < nnz; j++) {
      int    k  = kidx[j];
      float2 w  = wval[j];
      float2 cs = tw[(k * d) & (DD - 1)];
      re += w.x * cs.x + w.y * cs.y;          // W * e^{-i th}
      im += w.y * cs.x - w.x * cs.y;
    }
    T[(size_t)o * DD + d] = make_float2(re, im);
  }
}

// ---------------------------------------------------------------------------
// TT[d][o] = bf16(Re T[o][d]); TT[d][1024+o] = bf16(Im T[o][d])  (transpose)
// ---------------------------------------------------------------------------
__global__ __launch_bounds__(256) void transpose_T_kernel(
    const float2* __restrict__ T, unsigned short* __restrict__ TT) {
  __shared__ float2 tile[64][65];
  const int o0 = blockIdx.x * 64, d0 = blockIdx.y * 64;
  for (int q = threadIdx.x; q < 64 * 64; q += 256) {
    int r = q >> 6, c = q & 63;                 // r: o, c: d
    tile[r][c] = T[(size_t)(o0 + r) * DD + d0 + c];
  }
  __syncthreads();
  for (int q = threadIdx.x; q < 64 * 64; q += 256) {
    int r = q >> 6, c = q & 63;                 // r: d, c: o
    float2 v = tile[c][r];
    TT[(size_t)(d0 + r) * 2048 + o0 + c]        = f2bf(v.x);
    TT[(size_t)(d0 + r) * 2048 + 1024 + o0 + c] = f2bf(v.y);
  }
}

// ---------------------------------------------------------------------------
// CS[m][o] = bf16(cos(2pi m o/D)); CS[m][1024+o] = bf16(-sin(2pi m o/D))
// ---------------------------------------------------------------------------
__global__ __launch_bounds__(256) void gen_CS_kernel(unsigned short* __restrict__ CS) {
  int idx = blockIdx.x * 256 + threadIdx.x;     // 1M = 1024x1024
  int m = idx >> 10, o = idx & 1023;
  float s, c;
  sincosf((TWO_PI / DD) * (float)((m * o) & (DD - 1)), &s, &c);
  CS[(size_t)m * 2048 + o]        = f2bf(c);
  CS[(size_t)m * 2048 + 1024 + o] = f2bf(-s);
}

// ---------------------------------------------------------------------------
// x fp32 -> bf16 (8 elems/thread)
// ---------------------------------------------------------------------------
__global__ __launch_bounds__(256) void convert_x_kernel(
    const float* __restrict__ X, unsigned short* __restrict__ Xb) {
  size_t i = (size_t)blockIdx.x * 256 + threadIdx.x;   // chunk of 8
  const float4* p = (const float4*)(X + i * 8);
  float4 a = p[0], b = p[1];
  u16x8 v;
  v[0] = f2bf(a.x); v[1] = f2bf(a.y); v[2] = f2bf(a.z); v[3] = f2bf(a.w);
  v[4] = f2bf(b.x); v[5] = f2bf(b.y); v[6] = f2bf(b.z); v[7] = f2bf(b.w);
  *(u16x8*)(Xb + i * 8) = v;
}

// ---------------------------------------------------------------------------
// build_M (R3-proven): NT bf16 MFMA, 128x128 tile, BK=32, 2-barrier loop,
// split-K x4: P_z = CS(1024x2048) . TT^T over K-chunk z.
// ---------------------------------------------------------------------------
template <int LDK, int MODE>
__global__ __launch_bounds__(256) void mfma_nt_kernel(
    const unsigned short* __restrict__ A,
    const unsigned short* __restrict__ B,
    const float* __restrict__ bias,
    float* __restrict__ Out, float scale, int ldo, int kLen) {
  __shared__ __align__(16) unsigned short Asm[128 * 32];
  __shared__ __align__(16) unsigned short Bsm[128 * 32];
  const int tid  = threadIdx.x;
  const int wave = tid >> 6, lane = tid & 63;
  const int wr = wave >> 1, wc = wave & 1;
  const int row0 = blockIdx.y * 128;
  const int col0 = blockIdx.x * 128;
  const int kBeg = blockIdx.z * kLen;

  f32x4 acc[4][4] = {};

  for (int k0 = kBeg; k0 < kBeg + kLen; k0 += 32) {
    __syncthreads();
#pragma unroll
    for (int is = 0; is < 2; is++) {
      int e = is * 256 + tid;
      int r = e >> 2, c = (e & 3) * 8;
      const unsigned short* ga = A + (size_t)(row0 + r) * LDK + k0 + c;
      const unsigned short* gb = B + (size_t)(col0 + r) * LDK + k0 + c;
      __builtin_amdgcn_global_load_lds((g_void*)ga, (l_void*)(Asm + is * 2048 + wave * 512), 16, 0, 0);
      __builtin_amdgcn_global_load_lds((g_void*)gb, (l_void*)(Bsm + is * 2048 + wave * 512), 16, 0, 0);
    }
    __syncthreads();

    bf16x8 af[4], bfr[4];
#pragma unroll
    for (int i = 0; i < 4; i++) {
      int ra = wr * 64 + i * 16 + (lane & 15);
      af[i]  = *(const bf16x8*)&Asm[ra * 32 + (lane >> 4) * 8];
      int rb = wc * 64 + i * 16 + (lane & 15);
      bfr[i] = *(const bf16x8*)&Bsm[rb * 32 + (lane >> 4) * 8];
    }
#pragma unroll
    for (int i = 0; i < 4; i++)
#pragma unroll
      for (int j = 0; j < 4; j++)
        acc[i][j] = __builtin_amdgcn_mfma_f32_16x16x32_bf16(af[i], bfr[j], acc[i][j], 0, 0, 0);
  }

  const int crow0 = row0 + wr * 64;
  const int ccol0 = col0 + wc * 64;
  if (MODE == 2) {
    float* O = Out + (size_t)blockIdx.z * DD * DD;
#pragma unroll
    for (int i = 0; i < 4; i++)
#pragma unroll
      for (int j = 0; j < 4; j++) {
        int cc = ccol0 + j * 16 + (lane & 15);
#pragma unroll
        for (int v = 0; v < 4; v++) {
          int rr = crow0 + i * 16 + (lane >> 4) * 4 + v;
          O[(size_t)rr * ldo + cc] = acc[i][j][v];
        }
      }
  } else {
    float bv[4];
#pragma unroll
    for (int j = 0; j < 4; j++)
      bv[j] = bias[ccol0 + j * 16 + (lane & 15)];
#pragma unroll
    for (int i = 0; i < 4; i++)
#pragma unroll
      for (int j = 0; j < 4; j++) {
        int cc = ccol0 + j * 16 + (lane & 15);
#pragma unroll
        for (int v = 0; v < 4; v++) {
          int rr = crow0 + i * 16 + (lane >> 4) * 4 + v;
          Out[(size_t)rr * ldo + cc] = acc[i][j][v] * scale + bv[j];
        }
      }
  }
}

// ---------------------------------------------------------------------------
// Mb[i] = bf16( (P0[i]+P1[i]+P2[i]+P3[i]) / D ),  x4 vectorized.
// ---------------------------------------------------------------------------
__global__ __launch_bounds__(256) void reduce_M_kernel(
    const float* __restrict__ P, unsigned short* __restrict__ Mb) {
  const size_t NE = (size_t)DD * DD;
  size_t i = ((size_t)blockIdx.x * 256 + threadIdx.x) * 4;
  float4 s = *(const float4*)(P + i);
#pragma unroll
  for (int z = 1; z < 4; z++) {
    float4 p = *(const float4*)(P + z * NE + i);
    s.x += p.x; s.y += p.y; s.z += p.z; s.w += p.w;
  }
  const float inv = 1.0f / (float)DD;
  u16x4 v;
  v[0] = f2bf(s.x * inv); v[1] = f2bf(s.y * inv);
  v[2] = f2bf(s.z * inv); v[3] = f2bf(s.w * inv);
  *(u16x4*)(Mb + i) = v;
}

// ---------------------------------------------------------------------------
// gemm_y: Y[t][m] = sum_k Xb[t][k]*Mb[m][k] + bias[m]  (NT, bf16 MFMA)
// 128x128 tile, 4 waves (2x2), BK=64, double-buffered LDS, T3-minimum
// 2-phase schedule: per K-step issue STAGE(t+1) FIRST, then ds_read+MFMA(t),
// then ONE __syncthreads() (its drain is short: loads have been in flight
// under ~350 cyc of compute). 16 barrier-drains instead of R3's 32.
// LDS XOR swizzle (both-sides, rule #21): row stride 128B would be a 16-way
// bank conflict; store linearly from a pre-swizzled global column
// (chunk_src = (e&7)^((e>>3)&7)), read with chunk_phys = chunk_log ^ (row&7).
// 2-way after swizzle (free, m136).
// ---------------------------------------------------------------------------
__global__ __launch_bounds__(256) void gemm_y_kernel(
    const unsigned short* __restrict__ Xb,   // (8192 x 1024) bf16
    const unsigned short* __restrict__ Mb,   // (1024 x 1024) bf16
    const float* __restrict__ bias,
    float* __restrict__ Y) {
  __shared__ __align__(16) unsigned short Asm[2][128 * 64];
  __shared__ __align__(16) unsigned short Bsm[2][128 * 64];
  const int tid  = threadIdx.x;
  const int wave = tid >> 6, lane = tid & 63;
  const int wr = wave >> 1, wc = wave & 1;
  const int row0 = blockIdx.y * 128;
  const int col0 = blockIdx.x * 128;

  // e = p*256 + wave*64 + lane; LDS dest is wave-uniform base (+lane*16B HW);
  // source column pre-swizzled so that physical slot (r, s) holds global
  // chunk s ^ (r&7)  (chunks of 8 shorts = 16B).
#define STAGE(buf, kk)                                                        \
  {                                                                           \
    _Pragma("unroll")                                                         \
    for (int p = 0; p < 4; p++) {                                             \
      int e  = p * 256 + tid;                                                 \
      int r  = e >> 3;                                                        \
      int cs = ((e & 7) ^ ((e >> 3) & 7)) * 8;                                \
      const unsigned short* ga = Xb + (size_t)(row0 + r) * DD + (kk) + cs;    \
      const unsigned short* gb = Mb + (size_t)(col0 + r) * DD + (kk) + cs;    \
      __builtin_amdgcn_global_load_lds((g_void*)ga,                           \
          (l_void*)(Asm[buf] + p * 2048 + wave * 512), 16, 0, 0);             \
      __builtin_amdgcn_global_load_lds((g_void*)gb,                           \
          (l_void*)(Bsm[buf] + p * 2048 + wave * 512), 16, 0, 0);             \
    }                                                                         \
  }

  f32x4 acc[4][4] = {};

  STAGE(0, 0);
  __syncthreads();

  for (int t = 0; t < 16; ++t) {
    const int cur = t & 1;
    if (t < 15) STAGE(cur ^ 1, (t + 1) * 64);   // issue next tile first

#pragma unroll
    for (int half = 0; half < 2; half++) {
      bf16x8 af[4], bfr[4];
#pragma unroll
      for (int i = 0; i < 4; i++) {
        int ra = wr * 64 + i * 16 + (lane & 15);
        int ca = ((half * 4 + (lane >> 4)) ^ (ra & 7)) * 8;
        af[i]  = *(const bf16x8*)&Asm[cur][ra * 64 + ca];
        int rb = wc * 64 + i * 16 + (lane & 15);
        int cb = ((half * 4 + (lane >> 4)) ^ (rb & 7)) * 8;
        bfr[i] = *(const bf16x8*)&Bsm[cur][rb * 64 + cb];
      }
#pragma unroll
      for (int i = 0; i < 4; i++)
#pragma unroll
        for (int j = 0; j < 4; j++)
          acc[i][j] = __builtin_amdgcn_mfma_f32_16x16x32_bf16(af[i], bfr[j], acc[i][j], 0, 0, 0);
    }
    __syncthreads();   // drains staged loads; next buffer ready, cur reusable
  }
#undef STAGE

  const int crow0 = row0 + wr * 64;
  const int ccol0 = col0 + wc * 64;
  float bv[4];
#pragma unroll
  for (int j = 0; j < 4; j++)
    bv[j] = bias[ccol0 + j * 16 + (lane & 15)];
#pragma unroll
  for (int i = 0; i < 4; i++)
#pragma unroll
    for (int j = 0; j < 4; j++) {
      int cc = ccol0 + j * 16 + (lane & 15);
#pragma unroll
      for (int v = 0; v < 4; v++) {
        int rr = crow0 + i * 16 + (lane >> 4) * 4 + v;
        Y[(size_t)rr * DD + cc] = acc[i][j][v] + bv[j];
      }
    }
}

// ---------------------------------------------------------------------------
extern "C" void kernel_launch(void* const* d_in, const int* in_sizes, int n_in,
                              void* d_out, int out_size, void* d_ws, size_t ws_size,
                              hipStream_t stream) {
  const float* x    = (const float*)d_in[0];
  const float* wrp  = (const float*)d_in[1];
  const float* wip  = (const float*)d_in[2];
  const float* bias = (const float*)d_in[3];
  float*       y    = (float*)d_out;

  char* ws = (char*)d_ws;
  const size_t MB = 1024 * 1024;
  // 0..16MB time-shared: Wt (dead after build_T), T 8..16MB (dead after
  // transpose_T), then P partials, then Xb.
  float2*         Wt = (float2*)(ws + 0);                // 8 MB
  float2*         T  = (float2*)(ws + 8  * MB);          // 8 MB
  unsigned short* TT = (unsigned short*)(ws + 16 * MB);  // 4 MB  [d][2048]
  unsigned short* CS = (unsigned short*)(ws + 20 * MB);  // 4 MB  [m][2048]
  unsigned short* Mb = (unsigned short*)(ws + 24 * MB);  // 2 MB  [m][d]
  float*          P  = (float*)(ws + 0);                 // 16 MB partials
  unsigned short* Xb = (unsigned short*)(ws + 0);        // 16 MB (after reduce)

  transpose_W_kernel<<<dim3(16, 16), 256, 0, stream>>>(wrp, wip, Wt);
  build_T_kernel<<<DD, 256, 0, stream>>>(Wt, T);
  transpose_T_kernel<<<dim3(16, 16), 256, 0, stream>>>(T, TT);
  gen_CS_kernel<<<4096, 256, 0, stream>>>(CS);
  // P[z] = CS(1024x2048) . TT^T over K-chunk z of 512   (split-K x4)
  mfma_nt_kernel<2048, 2><<<dim3(8, 8, 4), 256, 0, stream>>>(
      CS, TT, nullptr, P, 1.0f, DD, 512);
  reduce_M_kernel<<<DD * DD / (256 * 4), 256, 0, stream>>>(P, Mb);
  convert_x_kernel<<<4096, 256, 0, stream>>>(x, Xb);
  // Y = Xb . Mb^T + bias  (BK=64 dbuf 2-phase, swizzled LDS)
  gemm_y_kernel<<<dim3(8, 64), 256, 0, stream>>>(Xb, Mb, bias, y);
}